// Round 2
// baseline (748.777 us; speedup 1.0000x reference)
//
#include <hip/hip_runtime.h>
#include <hip/hip_bf16.h>

#define T_SEQ 512
#define B_BAT 256
#define U_OSC 64
#define ED_ 100
#define PD_ 20
#define NC_ 2
#define NROW (T_SEQ * B_BAT)          // 131072 rows, row = t*256 + b
#define BU_ (B_BAT * U_OSC)           // 16384
#define PLANE ((size_t)NROW * U_OSC)  // 8388608 floats = 33.5 MB
#define DT_C 1e-3f
#define SC_C 0.2f
#define MU_C 1.0f
#define NSTEP 20

// ---------------------------------------------------------------------------
// K1: emb = E[x]; x1r = relu(emb@W1r+b1r); x1i = relu(emb@W1i+b1i)
// block: 128 rows x 128 cols (cols 0..63 = r-plane, 64..127 = i-plane)
// thread tile 8x8, K=100 staged in LDS.
// ---------------------------------------------------------------------------
__global__ __launch_bounds__(256) void k1_embed_proj(
    const int* __restrict__ xin, const float* __restrict__ E,
    const float* __restrict__ W1r, const float* __restrict__ b1r,
    const float* __restrict__ W1i, const float* __restrict__ b1i,
    float* __restrict__ outr, float* __restrict__ outi)
{
    __shared__ float embT[128 * 104];   // 53.2 KB, row stride 104 (100 padded)
    __shared__ float Wc[100 * 128];     // 51.2 KB, [k][c] c = r|i cat
    __shared__ float bias[128];
    const int tid = threadIdx.x;
    const int row0g = blockIdx.x * 128;

    for (int idx = tid; idx < 100 * 128; idx += 256) {
        int k = idx >> 7, c = idx & 127;
        Wc[idx] = (c < 64) ? W1r[k * 64 + c] : W1i[k * 64 + (c - 64)];
    }
    if (tid < 128) bias[tid] = (tid < 64) ? b1r[tid] : b1i[tid - 64];
    {   // gather embedding rows: 2 threads per row, float4
        int r = tid >> 1, half = tid & 1;
        int rg = row0g + r;
        int t = rg >> 8, b = rg & 255;
        int tok = xin[b * T_SEQ + t];
        const float4* src = (const float4*)(E + (size_t)tok * ED_);
        float4* dst = (float4*)&embT[r * 104];
        for (int j = half; j < 25; j += 2) dst[j] = src[j];
    }
    __syncthreads();

    const int col0 = (tid & 15) * 8;
    const int row0 = (tid >> 4) * 8;
    float acc[8][8];
#pragma unroll
    for (int i = 0; i < 8; ++i)
#pragma unroll
        for (int j = 0; j < 8; ++j) acc[i][j] = 0.f;

    for (int k0 = 0; k0 < 100; k0 += 4) {
        float ev[8][4];
#pragma unroll
        for (int i = 0; i < 8; ++i)
            *(float4*)ev[i] = *(const float4*)&embT[(row0 + i) * 104 + k0];
#pragma unroll
        for (int kk = 0; kk < 4; ++kk) {
            float4 wA = *(const float4*)&Wc[(k0 + kk) * 128 + col0];
            float4 wB = *(const float4*)&Wc[(k0 + kk) * 128 + col0 + 4];
#pragma unroll
            for (int i = 0; i < 8; ++i) {
                float e = ev[i][kk];
                acc[i][0] = fmaf(e, wA.x, acc[i][0]);
                acc[i][1] = fmaf(e, wA.y, acc[i][1]);
                acc[i][2] = fmaf(e, wA.z, acc[i][2]);
                acc[i][3] = fmaf(e, wA.w, acc[i][3]);
                acc[i][4] = fmaf(e, wB.x, acc[i][4]);
                acc[i][5] = fmaf(e, wB.y, acc[i][5]);
                acc[i][6] = fmaf(e, wB.z, acc[i][6]);
                acc[i][7] = fmaf(e, wB.w, acc[i][7]);
            }
        }
    }
    {
        float* plane = (col0 < 64) ? outr : outi;
        const int cc = col0 & 63;
#pragma unroll
        for (int i = 0; i < 8; ++i) {
            float4 o0, o1;
            o0.x = fmaxf(acc[i][0] + bias[col0 + 0], 0.f);
            o0.y = fmaxf(acc[i][1] + bias[col0 + 1], 0.f);
            o0.z = fmaxf(acc[i][2] + bias[col0 + 2], 0.f);
            o0.w = fmaxf(acc[i][3] + bias[col0 + 3], 0.f);
            o1.x = fmaxf(acc[i][4] + bias[col0 + 4], 0.f);
            o1.y = fmaxf(acc[i][5] + bias[col0 + 5], 0.f);
            o1.z = fmaxf(acc[i][6] + bias[col0 + 6], 0.f);
            o1.w = fmaxf(acc[i][7] + bias[col0 + 7], 0.f);
            size_t base = (size_t)(row0g + row0 + i) * 64 + cc;
            *(float4*)&plane[base] = o0;
            *(float4*)&plane[base + 4] = o1;
        }
    }
}

// ---------------------------------------------------------------------------
// Hopf oscillator scan: one thread per (b,u) chain. In-place safe (thread
// reads/writes only its own column; prefetch distance 2 tokens). NOTE: fr/fi
// alias zr_o/zi_o (in-place) — no __restrict__ here.
// Euler step rewritten as z' = g*z + w, g = C1 - DT*|z|^2 (chain depth 4).
// ---------------------------------------------------------------------------
__global__ __launch_bounds__(64) void hopf_seq(
    const float* fr, const float* fi,
    float* zr_o, float* zi_o,
    const float* __restrict__ omega)
{
    const int tid = blockIdx.x * 64 + threadIdx.x;   // b*64+u
    const float dom = DT_C * omega[tid & 63];
    const float C1 = 1.0f + DT_C * MU_C;
    const float SD = DT_C * SC_C;
    float zr = 0.1f, zi = 0.0f;
    float f0r = fr[tid], f0i = fi[tid];
    float f1r = fr[BU_ + tid], f1i = fi[BU_ + tid];
    for (int t = 0; t < T_SEQ; ++t) {
        float f2r = 0.f, f2i = 0.f;
        if (t + 2 < T_SEQ) {
            f2r = fr[(size_t)(t + 2) * BU_ + tid];
            f2i = fi[(size_t)(t + 2) * BU_ + tid];
        }
        const float dcr = SD * f0r, dci = SD * f0i;
#pragma unroll
        for (int s = 0; s < NSTEP; ++s) {
            float wr = fmaf(-dom, zi, dcr);
            float wi = fmaf( dom, zr, dci);
            float r2 = fmaf(zr, zr, zi * zi);
            float g  = fmaf(-DT_C, r2, C1);
            zr = fmaf(g, zr, wr);
            zi = fmaf(g, zi, wi);
        }
        zr_o[(size_t)t * BU_ + tid] = zr;
        zi_o[(size_t)t * BU_ + tid] = zi;
        f0r = f1r; f0i = f1i; f1r = f2r; f1i = f2i;
    }
}

// ---------------------------------------------------------------------------
// K3: h1 = relu([z1r|z1i]@Wp1+bp1); x2r = relu(h1@W2r+b2r); x2i likewise.
// In-place on the two planes (block stages its 128 rows to LDS first).
// ---------------------------------------------------------------------------
__global__ __launch_bounds__(256) void k3_mid(
    const float* __restrict__ zr_, const float* __restrict__ zi_,
    const float* __restrict__ Wp1, const float* __restrict__ bp1,
    const float* __restrict__ W2r, const float* __restrict__ b2r,
    const float* __restrict__ W2i, const float* __restrict__ b2i,
    float* __restrict__ xor_, float* __restrict__ xoi_)
{
    __shared__ float zt[128 * 128];   // 64 KB  [row][k] k = zr|zi cat
    __shared__ float Wa[128 * 64];    // 32 KB  Wp1, later reused as W2cat[64][128]
    __shared__ float h1t[128 * 68];   // 34.8 KB
    __shared__ float bp1s[64];
    __shared__ float b2s[128];
    const int tid = threadIdx.x;
    const int row0g = blockIdx.x * 128;

    for (int f = tid; f < 128 * 32; f += 256) {   // float4 stage of z tile
        int r = f >> 5, c = (f & 31) * 4;
        const float* srcp = (c < 64) ? (zr_ + (size_t)(row0g + r) * 64 + c)
                                     : (zi_ + (size_t)(row0g + r) * 64 + (c - 64));
        *(float4*)&zt[r * 128 + c] = *(const float4*)srcp;
    }
    for (int idx = tid; idx < 128 * 64; idx += 256) Wa[idx] = Wp1[idx];
    if (tid < 64) bp1s[tid] = bp1[tid];
    __syncthreads();

    {   // stage 1: h1, tile 8 rows x 4 cols, K=128
        const int col0 = (tid & 15) * 4;
        const int row0 = (tid >> 4) * 8;
        float acc[8][4];
#pragma unroll
        for (int i = 0; i < 8; ++i)
#pragma unroll
            for (int j = 0; j < 4; ++j) acc[i][j] = 0.f;
        for (int k0 = 0; k0 < 128; k0 += 4) {
            float zv[8][4];
#pragma unroll
            for (int i = 0; i < 8; ++i)
                *(float4*)zv[i] = *(const float4*)&zt[(row0 + i) * 128 + k0];
#pragma unroll
            for (int kk = 0; kk < 4; ++kk) {
                float4 w = *(const float4*)&Wa[(k0 + kk) * 64 + col0];
#pragma unroll
                for (int i = 0; i < 8; ++i) {
                    float z1 = zv[i][kk];
                    acc[i][0] = fmaf(z1, w.x, acc[i][0]);
                    acc[i][1] = fmaf(z1, w.y, acc[i][1]);
                    acc[i][2] = fmaf(z1, w.z, acc[i][2]);
                    acc[i][3] = fmaf(z1, w.w, acc[i][3]);
                }
            }
        }
#pragma unroll
        for (int i = 0; i < 8; ++i) {
            float4 o;
            o.x = fmaxf(acc[i][0] + bp1s[col0 + 0], 0.f);
            o.y = fmaxf(acc[i][1] + bp1s[col0 + 1], 0.f);
            o.z = fmaxf(acc[i][2] + bp1s[col0 + 2], 0.f);
            o.w = fmaxf(acc[i][3] + bp1s[col0 + 3], 0.f);
            *(float4*)&h1t[(row0 + i) * 68 + col0] = o;
        }
    }
    __syncthreads();
    for (int idx = tid; idx < 64 * 128; idx += 256) {   // restage Wa = W2cat
        int k = idx >> 7, c = idx & 127;
        Wa[idx] = (c < 64) ? W2r[k * 64 + c] : W2i[k * 64 + (c - 64)];
    }
    if (tid < 128) b2s[tid] = (tid < 64) ? b2r[tid] : b2i[tid - 64];
    __syncthreads();

    {   // stage 2: x2 = relu(h1@W2cat+b2), tile 8x8, K=64
        const int col0 = (tid & 15) * 8;
        const int row0 = (tid >> 4) * 8;
        float acc[8][8];
#pragma unroll
        for (int i = 0; i < 8; ++i)
#pragma unroll
            for (int j = 0; j < 8; ++j) acc[i][j] = 0.f;
        for (int k0 = 0; k0 < 64; k0 += 4) {
            float hv[8][4];
#pragma unroll
            for (int i = 0; i < 8; ++i)
                *(float4*)hv[i] = *(const float4*)&h1t[(row0 + i) * 68 + k0];
#pragma unroll
            for (int kk = 0; kk < 4; ++kk) {
                float4 wA = *(const float4*)&Wa[(k0 + kk) * 128 + col0];
                float4 wB = *(const float4*)&Wa[(k0 + kk) * 128 + col0 + 4];
#pragma unroll
                for (int i = 0; i < 8; ++i) {
                    float h = hv[i][kk];
                    acc[i][0] = fmaf(h, wA.x, acc[i][0]);
                    acc[i][1] = fmaf(h, wA.y, acc[i][1]);
                    acc[i][2] = fmaf(h, wA.z, acc[i][2]);
                    acc[i][3] = fmaf(h, wA.w, acc[i][3]);
                    acc[i][4] = fmaf(h, wB.x, acc[i][4]);
                    acc[i][5] = fmaf(h, wB.y, acc[i][5]);
                    acc[i][6] = fmaf(h, wB.z, acc[i][6]);
                    acc[i][7] = fmaf(h, wB.w, acc[i][7]);
                }
            }
        }
        float* plane = (col0 < 64) ? xor_ : xoi_;
        const int cc = col0 & 63;
#pragma unroll
        for (int i = 0; i < 8; ++i) {
            float4 o0, o1;
            o0.x = fmaxf(acc[i][0] + b2s[col0 + 0], 0.f);
            o0.y = fmaxf(acc[i][1] + b2s[col0 + 1], 0.f);
            o0.z = fmaxf(acc[i][2] + b2s[col0 + 2], 0.f);
            o0.w = fmaxf(acc[i][3] + b2s[col0 + 3], 0.f);
            o1.x = fmaxf(acc[i][4] + b2s[col0 + 4], 0.f);
            o1.y = fmaxf(acc[i][5] + b2s[col0 + 5], 0.f);
            o1.z = fmaxf(acc[i][6] + b2s[col0 + 6], 0.f);
            o1.w = fmaxf(acc[i][7] + b2s[col0 + 7], 0.f);
            size_t base = (size_t)(row0g + row0 + i) * 64 + cc;
            *(float4*)&plane[base] = o0;
            *(float4*)&plane[base + 4] = o1;
        }
    }
}

// ---------------------------------------------------------------------------
// K5: h2 = relu([z2r|z2i]@Wp2+bp2); h3 = tanh(h2@Wpr+bpr); out = h3@Wh+bh
// out written as float32, [B][T][NC] layout.
// ---------------------------------------------------------------------------
__global__ __launch_bounds__(256) void k5_out(
    const float* __restrict__ zr_, const float* __restrict__ zi_,
    const float* __restrict__ Wp2, const float* __restrict__ bp2,
    const float* __restrict__ Wpr, const float* __restrict__ bpr,
    const float* __restrict__ Wh,  const float* __restrict__ bh,
    float* __restrict__ out)
{
    __shared__ float zt[128 * 128];
    __shared__ float Wa[128 * 64];
    __shared__ float h2t[128 * 68];
    __shared__ float h3t[128 * 20];
    __shared__ float Wprs[64 * 20];
    __shared__ float bp2s[64];
    __shared__ float bprs[20];
    __shared__ float Whs[40];
    __shared__ float bhs[2];
    const int tid = threadIdx.x;
    const int row0g = blockIdx.x * 128;

    for (int f = tid; f < 128 * 32; f += 256) {
        int r = f >> 5, c = (f & 31) * 4;
        const float* srcp = (c < 64) ? (zr_ + (size_t)(row0g + r) * 64 + c)
                                     : (zi_ + (size_t)(row0g + r) * 64 + (c - 64));
        *(float4*)&zt[r * 128 + c] = *(const float4*)srcp;
    }
    for (int idx = tid; idx < 128 * 64; idx += 256) Wa[idx] = Wp2[idx];
    for (int idx = tid; idx < 64 * 20; idx += 256) Wprs[idx] = Wpr[idx];
    if (tid < 64) bp2s[tid] = bp2[tid];
    if (tid < 20) bprs[tid] = bpr[tid];
    if (tid < 40) Whs[tid] = Wh[tid];
    if (tid < 2)  bhs[tid] = bh[tid];
    __syncthreads();

    {   // h2 = relu(zcat@Wp2+bp2), tile 8x4, K=128
        const int col0 = (tid & 15) * 4;
        const int row0 = (tid >> 4) * 8;
        float acc[8][4];
#pragma unroll
        for (int i = 0; i < 8; ++i)
#pragma unroll
            for (int j = 0; j < 4; ++j) acc[i][j] = 0.f;
        for (int k0 = 0; k0 < 128; k0 += 4) {
            float zv[8][4];
#pragma unroll
            for (int i = 0; i < 8; ++i)
                *(float4*)zv[i] = *(const float4*)&zt[(row0 + i) * 128 + k0];
#pragma unroll
            for (int kk = 0; kk < 4; ++kk) {
                float4 w = *(const float4*)&Wa[(k0 + kk) * 64 + col0];
#pragma unroll
                for (int i = 0; i < 8; ++i) {
                    float z1 = zv[i][kk];
                    acc[i][0] = fmaf(z1, w.x, acc[i][0]);
                    acc[i][1] = fmaf(z1, w.y, acc[i][1]);
                    acc[i][2] = fmaf(z1, w.z, acc[i][2]);
                    acc[i][3] = fmaf(z1, w.w, acc[i][3]);
                }
            }
        }
#pragma unroll
        for (int i = 0; i < 8; ++i) {
            float4 o;
            o.x = fmaxf(acc[i][0] + bp2s[col0 + 0], 0.f);
            o.y = fmaxf(acc[i][1] + bp2s[col0 + 1], 0.f);
            o.z = fmaxf(acc[i][2] + bp2s[col0 + 2], 0.f);
            o.w = fmaxf(acc[i][3] + bp2s[col0 + 3], 0.f);
            *(float4*)&h2t[(row0 + i) * 68 + col0] = o;
        }
    }
    __syncthreads();

    {   // h3 = tanh(h2@Wpr+bpr): thread = (row, half of 20 cols)
        const int row = tid >> 1;
        const int c0 = (tid & 1) * 10;
        float a3[10];
#pragma unroll
        for (int j = 0; j < 10; ++j) a3[j] = 0.f;
        for (int k = 0; k < 64; ++k) {
            float hv = h2t[row * 68 + k];
#pragma unroll
            for (int j = 0; j < 10; ++j)
                a3[j] = fmaf(hv, Wprs[k * 20 + c0 + j], a3[j]);
        }
#pragma unroll
        for (int j = 0; j < 10; ++j)
            h3t[row * 20 + c0 + j] = tanhf(a3[j] + bprs[c0 + j]);
    }
    __syncthreads();

    {   // out = h3@Wh+bh, f32, [B][T][NC]
        const int row = tid >> 1, c = tid & 1;
        float a = bhs[c];
#pragma unroll
        for (int p = 0; p < 20; ++p)
            a = fmaf(h3t[row * 20 + p], Whs[p * 2 + c], a);
        int rg = row0g + row;
        int t = rg >> 8, b = rg & 255;
        out[(size_t)b * (T_SEQ * NC_) + t * NC_ + c] = a;
    }
}

// ---------------------------------------------------------------------------
extern "C" void kernel_launch(void* const* d_in, const int* in_sizes, int n_in,
                              void* d_out, int out_size, void* d_ws, size_t ws_size,
                              hipStream_t stream) {
    const int*   x   = (const int*)  d_in[0];
    const float* E   = (const float*)d_in[1];
    const float* W1r = (const float*)d_in[2];
    const float* b1r = (const float*)d_in[3];
    const float* W1i = (const float*)d_in[4];
    const float* b1i = (const float*)d_in[5];
    const float* om1 = (const float*)d_in[6];
    const float* Wp1 = (const float*)d_in[7];
    const float* bp1 = (const float*)d_in[8];
    const float* W2r = (const float*)d_in[9];
    const float* b2r = (const float*)d_in[10];
    const float* W2i = (const float*)d_in[11];
    const float* b2i = (const float*)d_in[12];
    const float* om2 = (const float*)d_in[13];
    const float* Wp2 = (const float*)d_in[14];
    const float* bp2 = (const float*)d_in[15];
    const float* Wpr = (const float*)d_in[16];
    const float* bpr = (const float*)d_in[17];
    const float* Wh  = (const float*)d_in[18];
    const float* bh  = (const float*)d_in[19];

    float* bufr = (float*)d_ws;        // [T][B][U] r-plane (x1/z1/x2/z2 in place)
    float* bufi = bufr + PLANE;        // i-plane

    k1_embed_proj<<<NROW / 128, 256, 0, stream>>>(x, E, W1r, b1r, W1i, b1i, bufr, bufi);
    hopf_seq<<<BU_ / 64, 64, 0, stream>>>(bufr, bufi, bufr, bufi, om1);
    k3_mid<<<NROW / 128, 256, 0, stream>>>(bufr, bufi, Wp1, bp1, W2r, b2r, W2i, b2i, bufr, bufi);
    hopf_seq<<<BU_ / 64, 64, 0, stream>>>(bufr, bufi, bufr, bufi, om2);
    k5_out<<<NROW / 128, 256, 0, stream>>>(bufr, bufi, Wp2, bp2, Wpr, bpr, Wh, bh,
                                           (float*)d_out);
}

// Round 3
// 509.931 us; speedup vs baseline: 1.4684x; 1.4684x over previous
//
#include <hip/hip_runtime.h>
#include <hip/hip_bf16.h>

#define T_SEQ 512
#define B_BAT 256
#define U_OSC 64
#define ED_ 100
#define PD_ 20
#define NC_ 2
#define NROW (T_SEQ * B_BAT)          // 131072 rows, row = t*256 + b
#define BU_ (B_BAT * U_OSC)           // 16384 chains
#define DT_C 1e-3f
#define SC_C 0.2f
#define MU_C 1.0f
#define NSTEP 20

// Workspace layout: single interleaved buffer zb[t][b][u][2] (r,i pairs),
// 512*256*64*2 floats = 67 MB. Used in place for x1/z1/x2/z2.
// Interleaved column index c in [0,128): u = c>>1, p = c&1 (0=r, 1=i).

// ---------------------------------------------------------------------------
// K1: emb = E[x]; zb[row][2u+p] = relu(emb@W1{r,i}+b1{r,i})
// block: 128 rows x 128 interleaved cols, thread tile 8x8, K=100 in LDS.
// ---------------------------------------------------------------------------
__global__ __launch_bounds__(256) void k1_embed_proj(
    const int* __restrict__ xin, const float* __restrict__ E,
    const float* __restrict__ W1r, const float* __restrict__ b1r,
    const float* __restrict__ W1i, const float* __restrict__ b1i,
    float* __restrict__ zb)
{
    __shared__ float embT[128 * 104];   // row stride 104 (100 padded)
    __shared__ float Wc[100 * 128];     // [k][c], c interleaved
    __shared__ float bias[128];
    const int tid = threadIdx.x;
    const int row0g = blockIdx.x * 128;

    for (int idx = tid; idx < 100 * 128; idx += 256) {
        int k = idx >> 7, c = idx & 127;
        Wc[idx] = (c & 1) ? W1i[k * 64 + (c >> 1)] : W1r[k * 64 + (c >> 1)];
    }
    if (tid < 128) bias[tid] = (tid & 1) ? b1i[tid >> 1] : b1r[tid >> 1];
    {   // gather embedding rows: 2 threads per row, float4
        int r = tid >> 1, half = tid & 1;
        int rg = row0g + r;
        int t = rg >> 8, b = rg & 255;
        int tok = xin[b * T_SEQ + t];
        const float4* src = (const float4*)(E + (size_t)tok * ED_);
        float4* dst = (float4*)&embT[r * 104];
        for (int j = half; j < 25; j += 2) dst[j] = src[j];
    }
    __syncthreads();

    const int col0 = (tid & 15) * 8;
    const int row0 = (tid >> 4) * 8;
    float acc[8][8];
#pragma unroll
    for (int i = 0; i < 8; ++i)
#pragma unroll
        for (int j = 0; j < 8; ++j) acc[i][j] = 0.f;

    for (int k0 = 0; k0 < 100; k0 += 4) {
        float ev[8][4];
#pragma unroll
        for (int i = 0; i < 8; ++i)
            *(float4*)ev[i] = *(const float4*)&embT[(row0 + i) * 104 + k0];
#pragma unroll
        for (int kk = 0; kk < 4; ++kk) {
            float4 wA = *(const float4*)&Wc[(k0 + kk) * 128 + col0];
            float4 wB = *(const float4*)&Wc[(k0 + kk) * 128 + col0 + 4];
#pragma unroll
            for (int i = 0; i < 8; ++i) {
                float e = ev[i][kk];
                acc[i][0] = fmaf(e, wA.x, acc[i][0]);
                acc[i][1] = fmaf(e, wA.y, acc[i][1]);
                acc[i][2] = fmaf(e, wA.z, acc[i][2]);
                acc[i][3] = fmaf(e, wA.w, acc[i][3]);
                acc[i][4] = fmaf(e, wB.x, acc[i][4]);
                acc[i][5] = fmaf(e, wB.y, acc[i][5]);
                acc[i][6] = fmaf(e, wB.z, acc[i][6]);
                acc[i][7] = fmaf(e, wB.w, acc[i][7]);
            }
        }
    }
#pragma unroll
    for (int i = 0; i < 8; ++i) {
        float4 o0, o1;
        o0.x = fmaxf(acc[i][0] + bias[col0 + 0], 0.f);
        o0.y = fmaxf(acc[i][1] + bias[col0 + 1], 0.f);
        o0.z = fmaxf(acc[i][2] + bias[col0 + 2], 0.f);
        o0.w = fmaxf(acc[i][3] + bias[col0 + 3], 0.f);
        o1.x = fmaxf(acc[i][4] + bias[col0 + 4], 0.f);
        o1.y = fmaxf(acc[i][5] + bias[col0 + 5], 0.f);
        o1.z = fmaxf(acc[i][6] + bias[col0 + 6], 0.f);
        o1.w = fmaxf(acc[i][7] + bias[col0 + 7], 0.f);
        size_t base = (size_t)(row0g + row0 + i) * 128 + col0;
        *(float4*)&zb[base] = o0;
        *(float4*)&zb[base + 4] = o1;
    }
}

// ---------------------------------------------------------------------------
// Hopf oscillator scan, in-place on zb. One thread per (b,u) chain.
// t-loop unrolled x4 with named prefetch ring (distance 4) and output
// staging ring so store-data registers are not reused for ~4 tokens.
// Euler step: z' = g*z + w, g = C1 - DT*|z|^2 (3-FMA dep chain).
// ---------------------------------------------------------------------------
__global__ __launch_bounds__(64) void hopf_seq(
    float* zb, const float* __restrict__ omega)
{
    const int cid = blockIdx.x * 64 + threadIdx.x;   // b*64+u
    const float dom = DT_C * omega[cid & 63];
    const float C1 = 1.0f + DT_C * MU_C;
    const float SD = DT_C * SC_C;
    const size_t TSTR = (size_t)BU_ * 2;             // floats per token
    float* base = zb + (size_t)cid * 2;

    float zr = 0.1f, zi = 0.0f;
    float2 pf[4];
#pragma unroll
    for (int j = 0; j < 4; ++j)
        pf[j] = *(const float2*)(base + (size_t)j * TSTR);

    float2 oz[4];
    for (int t0 = 0; t0 < T_SEQ; t0 += 4) {
#pragma unroll
        for (int j = 0; j < 4; ++j) {
            const int t = t0 + j;
            const float dcr = SD * pf[j].x, dci = SD * pf[j].y;
            const int tp = (t + 4 < T_SEQ) ? (t + 4) : (T_SEQ - 1);
            pf[j] = *(const float2*)(base + (size_t)tp * TSTR);
#pragma unroll
            for (int s = 0; s < NSTEP; ++s) {
                float wr = fmaf(-dom, zi, dcr);
                float wi = fmaf( dom, zr, dci);
                float r2 = fmaf(zr, zr, zi * zi);
                float g  = fmaf(-DT_C, r2, C1);
                zr = fmaf(g, zr, wr);
                zi = fmaf(g, zi, wi);
            }
            oz[j].x = zr; oz[j].y = zi;
            *(float2*)(base + (size_t)t * TSTR) = oz[j];
        }
    }
}

// ---------------------------------------------------------------------------
// K3: h1 = relu(zcat@Wp1+bp1); x2 = relu(h1@W2cat+b2cat), in place on zb.
// zcat columns are interleaved -> Wp1 rows permuted at LDS-stage time.
// ---------------------------------------------------------------------------
__global__ __launch_bounds__(256) void k3_mid(
    float* zb,
    const float* __restrict__ Wp1, const float* __restrict__ bp1,
    const float* __restrict__ W2r, const float* __restrict__ b2r,
    const float* __restrict__ W2i, const float* __restrict__ b2i)
{
    __shared__ float zt[128 * 128];   // [row][kI] kI interleaved
    __shared__ float Wa[128 * 64];    // Wp1 (rows permuted), then W2cat[64][128]
    __shared__ float h1t[128 * 68];
    __shared__ float bp1s[64];
    __shared__ float b2s[128];
    const int tid = threadIdx.x;
    const int row0g = blockIdx.x * 128;

    for (int f = tid; f < 128 * 32; f += 256) {   // contiguous float4 stage
        int r = f >> 5, c = (f & 31) * 4;
        *(float4*)&zt[r * 128 + c] =
            *(const float4*)&zb[(size_t)(row0g + r) * 128 + c];
    }
    for (int idx = tid; idx < 128 * 64; idx += 256) {
        int kI = idx >> 6, c = idx & 63;           // kI interleaved
        int kRef = (kI & 1) * 64 + (kI >> 1);      // reference concat row
        Wa[idx] = Wp1[kRef * 64 + c];
    }
    if (tid < 64) bp1s[tid] = bp1[tid];
    __syncthreads();

    {   // stage 1: h1, tile 8 rows x 4 cols, K=128
        const int col0 = (tid & 15) * 4;
        const int row0 = (tid >> 4) * 8;
        float acc[8][4];
#pragma unroll
        for (int i = 0; i < 8; ++i)
#pragma unroll
            for (int j = 0; j < 4; ++j) acc[i][j] = 0.f;
        for (int k0 = 0; k0 < 128; k0 += 4) {
            float zv[8][4];
#pragma unroll
            for (int i = 0; i < 8; ++i)
                *(float4*)zv[i] = *(const float4*)&zt[(row0 + i) * 128 + k0];
#pragma unroll
            for (int kk = 0; kk < 4; ++kk) {
                float4 w = *(const float4*)&Wa[(k0 + kk) * 64 + col0];
#pragma unroll
                for (int i = 0; i < 8; ++i) {
                    float z1 = zv[i][kk];
                    acc[i][0] = fmaf(z1, w.x, acc[i][0]);
                    acc[i][1] = fmaf(z1, w.y, acc[i][1]);
                    acc[i][2] = fmaf(z1, w.z, acc[i][2]);
                    acc[i][3] = fmaf(z1, w.w, acc[i][3]);
                }
            }
        }
#pragma unroll
        for (int i = 0; i < 8; ++i) {
            float4 o;
            o.x = fmaxf(acc[i][0] + bp1s[col0 + 0], 0.f);
            o.y = fmaxf(acc[i][1] + bp1s[col0 + 1], 0.f);
            o.z = fmaxf(acc[i][2] + bp1s[col0 + 2], 0.f);
            o.w = fmaxf(acc[i][3] + bp1s[col0 + 3], 0.f);
            *(float4*)&h1t[(row0 + i) * 68 + col0] = o;
        }
    }
    __syncthreads();
    for (int idx = tid; idx < 64 * 128; idx += 256) {   // Wa = W2cat, cols interleaved
        int k = idx >> 7, c = idx & 127;
        Wa[idx] = (c & 1) ? W2i[k * 64 + (c >> 1)] : W2r[k * 64 + (c >> 1)];
    }
    if (tid < 128) b2s[tid] = (tid & 1) ? b2i[tid >> 1] : b2r[tid >> 1];
    __syncthreads();

    {   // stage 2: x2 = relu(h1@W2cat+b2), tile 8x8, K=64, write interleaved
        const int col0 = (tid & 15) * 8;
        const int row0 = (tid >> 4) * 8;
        float acc[8][8];
#pragma unroll
        for (int i = 0; i < 8; ++i)
#pragma unroll
            for (int j = 0; j < 8; ++j) acc[i][j] = 0.f;
        for (int k0 = 0; k0 < 64; k0 += 4) {
            float hv[8][4];
#pragma unroll
            for (int i = 0; i < 8; ++i)
                *(float4*)hv[i] = *(const float4*)&h1t[(row0 + i) * 68 + k0];
#pragma unroll
            for (int kk = 0; kk < 4; ++kk) {
                float4 wA = *(const float4*)&Wa[(k0 + kk) * 128 + col0];
                float4 wB = *(const float4*)&Wa[(k0 + kk) * 128 + col0 + 4];
#pragma unroll
                for (int i = 0; i < 8; ++i) {
                    float h = hv[i][kk];
                    acc[i][0] = fmaf(h, wA.x, acc[i][0]);
                    acc[i][1] = fmaf(h, wA.y, acc[i][1]);
                    acc[i][2] = fmaf(h, wA.z, acc[i][2]);
                    acc[i][3] = fmaf(h, wA.w, acc[i][3]);
                    acc[i][4] = fmaf(h, wB.x, acc[i][4]);
                    acc[i][5] = fmaf(h, wB.y, acc[i][5]);
                    acc[i][6] = fmaf(h, wB.z, acc[i][6]);
                    acc[i][7] = fmaf(h, wB.w, acc[i][7]);
                }
            }
        }
#pragma unroll
        for (int i = 0; i < 8; ++i) {
            float4 o0, o1;
            o0.x = fmaxf(acc[i][0] + b2s[col0 + 0], 0.f);
            o0.y = fmaxf(acc[i][1] + b2s[col0 + 1], 0.f);
            o0.z = fmaxf(acc[i][2] + b2s[col0 + 2], 0.f);
            o0.w = fmaxf(acc[i][3] + b2s[col0 + 3], 0.f);
            o1.x = fmaxf(acc[i][4] + b2s[col0 + 4], 0.f);
            o1.y = fmaxf(acc[i][5] + b2s[col0 + 5], 0.f);
            o1.z = fmaxf(acc[i][6] + b2s[col0 + 6], 0.f);
            o1.w = fmaxf(acc[i][7] + b2s[col0 + 7], 0.f);
            size_t base = (size_t)(row0g + row0 + i) * 128 + col0;
            *(float4*)&zb[base] = o0;
            *(float4*)&zb[base + 4] = o1;
        }
    }
}

// ---------------------------------------------------------------------------
// K5: h2 = relu(zcat@Wp2+bp2); h3 = tanh(h2@Wpr+bpr); out = h3@Wh+bh (f32)
// ---------------------------------------------------------------------------
__global__ __launch_bounds__(256) void k5_out(
    const float* __restrict__ zb,
    const float* __restrict__ Wp2, const float* __restrict__ bp2,
    const float* __restrict__ Wpr, const float* __restrict__ bpr,
    const float* __restrict__ Wh,  const float* __restrict__ bh,
    float* __restrict__ out)
{
    __shared__ float zt[128 * 128];
    __shared__ float Wa[128 * 64];
    __shared__ float h2t[128 * 68];
    __shared__ float h3t[128 * 20];
    __shared__ float Wprs[64 * 20];
    __shared__ float bp2s[64];
    __shared__ float bprs[20];
    __shared__ float Whs[40];
    __shared__ float bhs[2];
    const int tid = threadIdx.x;
    const int row0g = blockIdx.x * 128;

    for (int f = tid; f < 128 * 32; f += 256) {
        int r = f >> 5, c = (f & 31) * 4;
        *(float4*)&zt[r * 128 + c] =
            *(const float4*)&zb[(size_t)(row0g + r) * 128 + c];
    }
    for (int idx = tid; idx < 128 * 64; idx += 256) {
        int kI = idx >> 6, c = idx & 63;
        int kRef = (kI & 1) * 64 + (kI >> 1);
        Wa[idx] = Wp2[kRef * 64 + c];
    }
    for (int idx = tid; idx < 64 * 20; idx += 256) Wprs[idx] = Wpr[idx];
    if (tid < 64) bp2s[tid] = bp2[tid];
    if (tid < 20) bprs[tid] = bpr[tid];
    if (tid < 40) Whs[tid] = Wh[tid];
    if (tid < 2)  bhs[tid] = bh[tid];
    __syncthreads();

    {   // h2 = relu(zcat@Wp2+bp2), tile 8x4, K=128
        const int col0 = (tid & 15) * 4;
        const int row0 = (tid >> 4) * 8;
        float acc[8][4];
#pragma unroll
        for (int i = 0; i < 8; ++i)
#pragma unroll
            for (int j = 0; j < 4; ++j) acc[i][j] = 0.f;
        for (int k0 = 0; k0 < 128; k0 += 4) {
            float zv[8][4];
#pragma unroll
            for (int i = 0; i < 8; ++i)
                *(float4*)zv[i] = *(const float4*)&zt[(row0 + i) * 128 + k0];
#pragma unroll
            for (int kk = 0; kk < 4; ++kk) {
                float4 w = *(const float4*)&Wa[(k0 + kk) * 64 + col0];
#pragma unroll
                for (int i = 0; i < 8; ++i) {
                    float z1 = zv[i][kk];
                    acc[i][0] = fmaf(z1, w.x, acc[i][0]);
                    acc[i][1] = fmaf(z1, w.y, acc[i][1]);
                    acc[i][2] = fmaf(z1, w.z, acc[i][2]);
                    acc[i][3] = fmaf(z1, w.w, acc[i][3]);
                }
            }
        }
#pragma unroll
        for (int i = 0; i < 8; ++i) {
            float4 o;
            o.x = fmaxf(acc[i][0] + bp2s[col0 + 0], 0.f);
            o.y = fmaxf(acc[i][1] + bp2s[col0 + 1], 0.f);
            o.z = fmaxf(acc[i][2] + bp2s[col0 + 2], 0.f);
            o.w = fmaxf(acc[i][3] + bp2s[col0 + 3], 0.f);
            *(float4*)&h2t[(row0 + i) * 68 + col0] = o;
        }
    }
    __syncthreads();

    {   // h3 = tanh(h2@Wpr+bpr)
        const int row = tid >> 1;
        const int c0 = (tid & 1) * 10;
        float a3[10];
#pragma unroll
        for (int j = 0; j < 10; ++j) a3[j] = 0.f;
        for (int k = 0; k < 64; ++k) {
            float hv = h2t[row * 68 + k];
#pragma unroll
            for (int j = 0; j < 10; ++j)
                a3[j] = fmaf(hv, Wprs[k * 20 + c0 + j], a3[j]);
        }
#pragma unroll
        for (int j = 0; j < 10; ++j)
            h3t[row * 20 + c0 + j] = tanhf(a3[j] + bprs[c0 + j]);
    }
    __syncthreads();

    {   // out = h3@Wh+bh, f32, [B][T][NC]
        const int row = tid >> 1, c = tid & 1;
        float a = bhs[c];
#pragma unroll
        for (int p = 0; p < 20; ++p)
            a = fmaf(h3t[row * 20 + p], Whs[p * 2 + c], a);
        int rg = row0g + row;
        int t = rg >> 8, b = rg & 255;
        out[(size_t)b * (T_SEQ * NC_) + t * NC_ + c] = a;
    }
}

// ---------------------------------------------------------------------------
extern "C" void kernel_launch(void* const* d_in, const int* in_sizes, int n_in,
                              void* d_out, int out_size, void* d_ws, size_t ws_size,
                              hipStream_t stream) {
    const int*   x   = (const int*)  d_in[0];
    const float* E   = (const float*)d_in[1];
    const float* W1r = (const float*)d_in[2];
    const float* b1r = (const float*)d_in[3];
    const float* W1i = (const float*)d_in[4];
    const float* b1i = (const float*)d_in[5];
    const float* om1 = (const float*)d_in[6];
    const float* Wp1 = (const float*)d_in[7];
    const float* bp1 = (const float*)d_in[8];
    const float* W2r = (const float*)d_in[9];
    const float* b2r = (const float*)d_in[10];
    const float* W2i = (const float*)d_in[11];
    const float* b2i = (const float*)d_in[12];
    const float* om2 = (const float*)d_in[13];
    const float* Wp2 = (const float*)d_in[14];
    const float* bp2 = (const float*)d_in[15];
    const float* Wpr = (const float*)d_in[16];
    const float* bpr = (const float*)d_in[17];
    const float* Wh  = (const float*)d_in[18];
    const float* bh  = (const float*)d_in[19];

    float* zb = (float*)d_ws;   // [T][B][U][2] interleaved r,i — 67 MB

    k1_embed_proj<<<NROW / 128, 256, 0, stream>>>(x, E, W1r, b1r, W1i, b1i, zb);
    hopf_seq<<<BU_ / 64, 64, 0, stream>>>(zb, om1);
    k3_mid<<<NROW / 128, 256, 0, stream>>>(zb, Wp1, bp1, W2r, b2r, W2i, b2i);
    hopf_seq<<<BU_ / 64, 64, 0, stream>>>(zb, om2);
    k5_out<<<NROW / 128, 256, 0, stream>>>(zb, Wp2, bp2, Wpr, bpr, Wh, bh,
                                           (float*)d_out);
}